// Round 1
// baseline (234.864 us; speedup 1.0000x reference)
//
#include <hip/hip_runtime.h>
#include <stdint.h>

// ---------------- modular arithmetic (Montgomery, R = 2^32) ----------------
static constexpr uint32_t P = 2013265921u;         // 15*2^27 + 1
static constexpr int      LOGM = 11;               // small DFT size 2048
static constexpr int      MSZ  = 1 << LOGM;        // 2048
static constexpr uint32_t NHALF = 1u << 21;        // twiddle table length N/2

__host__ __device__ constexpr uint32_t neg_pinv32() {
    uint32_t x = 1u;                                // Newton: x = P^-1 mod 2^32
    for (int i = 0; i < 5; ++i) x *= 2u - P * x;
    return 0u - x;                                  // -P^-1 mod 2^32
}
static constexpr uint32_t NEG_PINV = neg_pinv32();
static constexpr uint32_t R1 = (uint32_t)(((uint64_t)1 << 32) % P);
static constexpr uint32_t R2 = (uint32_t)(((uint64_t)R1 * R1) % P);

__device__ __forceinline__ uint32_t mont_mul(uint32_t a, uint32_t b) {
    uint64_t t = (uint64_t)a * (uint64_t)b;
    uint32_t m = (uint32_t)t * NEG_PINV;
    uint32_t r = (uint32_t)((t + (uint64_t)m * P) >> 32);
    return r >= P ? r - P : r;
}
__device__ __forceinline__ uint32_t to_mont(uint32_t a) { return mont_mul(a, R2); }
__device__ __forceinline__ uint32_t add_p(uint32_t a, uint32_t b) {
    uint32_t r = a + b; return r >= P ? r - P : r;
}
__device__ __forceinline__ uint32_t sub_p(uint32_t a, uint32_t b) {
    return a >= b ? a - b : a + P - b;
}

// ---------------- kernel 0: Montgomery stage-twiddle table -----------------
// rtab_g[e] = Mont(w^(2048*e)), e in [0,1024). Rebuilt every call (ws poisoned).
__global__ void build_rtab(const uint32_t* __restrict__ tw, uint32_t* __restrict__ rtab_g) {
    int e = threadIdx.x;
    if (e < MSZ / 2) rtab_g[e] = to_mont(tw[(uint32_t)e << LOGM]);
}

// ---------------- main pass: one 2048-pt DFT per workgroup -----------------
// PASS2=false: read x[i2*2048+col] (strided), DFT over i2, multiply w^{col*k2},
//              write T[col*2048+k2] (contiguous) into dst.
// PASS2=true : read T[i1*2048+col] (strided), DFT over i1, multiply n_inv,
//              write out[k1*2048+col] (strided; same address set as the read
//              -> safe fully-in-place per column).
template <bool PASS2>
__global__ __launch_bounds__(256) void intt_pass(
        const uint4* src, uint4* dst,
        const uint32_t* __restrict__ tw,
        const uint32_t* __restrict__ rtab_g,
        const uint32_t* __restrict__ ninv_p)
{
    __shared__ uint4    buf[MSZ];        // 32 KiB: 4 batch columns per element
    __shared__ uint32_t rtab[MSZ / 2];   // 4 KiB Montgomery stage twiddles

    const int      tid = threadIdx.x;
    const uint32_t bid = blockIdx.x;
    // XCD swizzle: adjacent columns (sharing 64B lines) map to one XCD's L2
    const uint32_t col = ((bid & 7u) << 8) | (bid >> 3);

    for (int e = tid; e < MSZ / 2; e += 256) rtab[e] = rtab_g[e];

    // load with bit-reversal folded into the (already strided/cached) global read
#pragma unroll
    for (int r = 0; r < 8; ++r) {
        int p = tid + (r << 8);
        uint32_t rv = __brev((uint32_t)p) >> (32 - LOGM);
        buf[p] = src[rv * (uint32_t)MSZ + col];
    }
    __syncthreads();

    // 11 radix-2 DIT stages, natural-order output
    for (int s = 1; s <= LOGM; ++s) {
        const int half = 1 << (s - 1);
#pragma unroll
        for (int r = 0; r < 4; ++r) {
            int b  = tid + (r << 8);              // butterfly id, < 1024
            int j  = b & (half - 1);
            int lo = ((b >> (s - 1)) << s) | j;
            int hi = lo + half;
            uint32_t wm = rtab[j << (LOGM - s)];  // Mont(root^{(M/m) j})
            uint4 L = buf[lo];
            uint4 H = buf[hi];
            uint32_t tx = mont_mul(wm, H.x);
            uint32_t ty = mont_mul(wm, H.y);
            uint32_t tz = mont_mul(wm, H.z);
            uint32_t tww = mont_mul(wm, H.w);
            buf[lo] = make_uint4(add_p(L.x, tx), add_p(L.y, ty),
                                 add_p(L.z, tz), add_p(L.w, tww));
            buf[hi] = make_uint4(sub_p(L.x, tx), sub_p(L.y, ty),
                                 sub_p(L.z, tz), sub_p(L.w, tww));
        }
        __syncthreads();
    }

    if (!PASS2) {
        // middle twiddle w^{col*k2}, computed incrementally in Montgomery form:
        //   start = Mont(w^{col*tid}), step = Mont(w^{col*256})
        // exponents col*tid, col*256 < 2^21 -> direct table lookup, no wrap.
        uint32_t tm   = to_mont(tw[col * (uint32_t)tid]);
        uint32_t step = to_mont(tw[col << 8]);
#pragma unroll
        for (int r = 0; r < 8; ++r) {
            int k2 = tid + (r << 8);
            uint4 v = buf[k2];
            dst[col * (uint32_t)MSZ + (uint32_t)k2] =
                make_uint4(mont_mul(tm, v.x), mont_mul(tm, v.y),
                           mont_mul(tm, v.z), mont_mul(tm, v.w));
            tm = mont_mul(tm, step);
        }
    } else {
        uint32_t nm = to_mont(*ninv_p);
#pragma unroll
        for (int r = 0; r < 8; ++r) {
            int k1 = tid + (r << 8);
            uint4 v = buf[k1];
            dst[(uint32_t)k1 * (uint32_t)MSZ + col] =
                make_uint4(mont_mul(nm, v.x), mont_mul(nm, v.y),
                           mont_mul(nm, v.z), mont_mul(nm, v.w));
        }
    }
}

// ------------------------------- launch ------------------------------------
extern "C" void kernel_launch(void* const* d_in, const int* in_sizes, int n_in,
                              void* d_out, int out_size, void* d_ws, size_t ws_size,
                              hipStream_t stream)
{
    const uint4*    x    = (const uint4*)d_in[0];      // (N, 4) int32 rows
    const uint32_t* tw   = (const uint32_t*)d_in[1];   // w^k, k < 2^21
    const uint32_t* ninv = (const uint32_t*)d_in[2];
    uint4*          out  = (uint4*)d_out;
    uint32_t*       rtab_g = (uint32_t*)d_ws;          // 4 KiB

    build_rtab<<<dim3(1), dim3(1024), 0, stream>>>(tw, rtab_g);
    intt_pass<false><<<dim3(2048), dim3(256), 0, stream>>>(x, out, tw, rtab_g, ninv);
    intt_pass<true ><<<dim3(2048), dim3(256), 0, stream>>>(out, out, tw, rtab_g, ninv);
}

// Round 2
// 216.478 us; speedup vs baseline: 1.0849x; 1.0849x over previous
//
#include <hip/hip_runtime.h>
#include <stdint.h>

// ---------------- modular arithmetic (Montgomery, R = 2^32) ----------------
static constexpr uint32_t P = 2013265921u;         // 15*2^27 + 1
static constexpr int      LOGM = 11;               // per-block DFT size 2048
static constexpr int      MSZ  = 1 << LOGM;

__host__ __device__ constexpr uint32_t neg_pinv32() {
    uint32_t x = 1u;
    for (int i = 0; i < 5; ++i) x *= 2u - P * x;
    return 0u - x;
}
static constexpr uint32_t NEG_PINV = neg_pinv32();
static constexpr uint32_t R1 = (uint32_t)(((uint64_t)1 << 32) % P);
static constexpr uint32_t R2 = (uint32_t)(((uint64_t)R1 * R1) % P);

__device__ __forceinline__ uint32_t mont_mul(uint32_t a, uint32_t b) {
    uint64_t t = (uint64_t)a * (uint64_t)b;
    uint32_t m = (uint32_t)t * NEG_PINV;
    uint32_t r = (uint32_t)((t + (uint64_t)m * P) >> 32);   // r < 2P
    uint32_t s = r - P;
    return s < r ? s : r;                                    // min-trick reduce
}
__device__ __forceinline__ uint32_t to_mont(uint32_t a) { return mont_mul(a, R2); }
__device__ __forceinline__ uint32_t add_p(uint32_t a, uint32_t b) {
    uint32_t r = a + b, s = r - P; return s < r ? s : r;
}
__device__ __forceinline__ uint32_t sub_p(uint32_t a, uint32_t b) {
    uint32_t r = a - b, s = r + P; return s < r ? s : r;     // wraps iff a<b
}

__device__ __forceinline__ uint4 mm4(uint32_t w, uint4 v) {
    return make_uint4(mont_mul(w, v.x), mont_mul(w, v.y),
                      mont_mul(w, v.z), mont_mul(w, v.w));
}
__device__ __forceinline__ void bf4(uint4& L, uint4& H, uint32_t w) {
    uint4 t = mm4(w, H);
    uint4 l = L;
    L = make_uint4(add_p(l.x, t.x), add_p(l.y, t.y), add_p(l.z, t.z), add_p(l.w, t.w));
    H = make_uint4(sub_p(l.x, t.x), sub_p(l.y, t.y), sub_p(l.z, t.z), sub_p(l.w, t.w));
}

// LDS index swizzle: XOR low 3 bits with bits [3:6)^[6:9) — bijective, and
// conflict-free (full 32-bank spread per lane-octet) for every access stride
// used below (1, 8, 64, 512). No padding -> buf stays 32 KiB.
__device__ __forceinline__ int fmap(int i) {
    return i ^ (((i >> 3) ^ (i >> 6)) & 7);
}

// 3 DIT stages (radix-8) fully in registers.
__device__ __forceinline__ void radix8(uint4 x[8],
        uint32_t ta, uint32_t tb0, uint32_t tb1,
        uint32_t tc0, uint32_t tc1, uint32_t tc2, uint32_t tc3) {
    bf4(x[0], x[1], ta);  bf4(x[2], x[3], ta);
    bf4(x[4], x[5], ta);  bf4(x[6], x[7], ta);
    bf4(x[0], x[2], tb0); bf4(x[1], x[3], tb1);
    bf4(x[4], x[6], tb0); bf4(x[5], x[7], tb1);
    bf4(x[0], x[4], tc0); bf4(x[1], x[5], tc1);
    bf4(x[2], x[6], tc2); bf4(x[3], x[7], tc3);
}

// One 2048-pt inverse-DFT per workgroup over 4 batch columns (uint4/element).
// PASS1: src rows are x[i2*2048 + col]; output T[col*2048 + k2] * w^(col*k2).
// PASS2: src rows are T[i1*2048 + col]; output out[k1*2048 + col] * n_inv
//        (same per-column address set read/written -> in-place safe).
template <bool PASS2>
__global__ __launch_bounds__(256, 4) void intt_pass(
        const uint4* __restrict__ src, uint4* __restrict__ dst,
        const uint32_t* __restrict__ tw,
        const uint32_t* __restrict__ ninv_p)
{
    __shared__ uint4    buf[MSZ];        // 32 KiB
    __shared__ uint32_t rtab[MSZ / 2];   // 4 KiB Montgomery stage twiddles

    const int      tid = threadIdx.x;
    const uint32_t bid = blockIdx.x;
    // XCD swizzle: adjacent columns (sharing 64B lines) land on one XCD's L2
    const uint32_t col = ((bid & 7u) << 8) | (bid >> 3);

    // stage-twiddle gather (issue first; L2-hot after first blocks)
    uint32_t tv[4];
#pragma unroll
    for (int j = 0; j < 4; ++j)
        tv[j] = tw[(uint32_t)(tid + 256 * j) << LOGM];

    // phase-0 global gather with bit-reversal folded in:
    // buf index 8*tid+m  <-  src row rev11(8*tid+m) = rev3(m)<<8 | rev8(tid)
    const uint32_t r8 = __brev((uint32_t)tid) >> 24;
    uint4 x[8];
#pragma unroll
    for (int m = 0; m < 8; ++m) {
        uint32_t r3 = __brev((uint32_t)m) >> 29;
        x[m] = src[((r3 << 8) | r8) * (uint32_t)MSZ + col];
    }
#pragma unroll
    for (int j = 0; j < 4; ++j)
        rtab[tid + 256 * j] = to_mont(tv[j]);
    __syncthreads();

    // ---- phase 0: stages 1-3 (L = 0) ----
    radix8(x, rtab[0], rtab[0], rtab[512],
              rtab[0], rtab[256], rtab[512], rtab[768]);
#pragma unroll
    for (int m = 0; m < 8; ++m) buf[fmap(8 * tid + m)] = x[m];
    __syncthreads();

    // ---- phase 1: stages 4-6 (element stride 8) ----
    {
        const int L = tid & 7, hi = tid >> 3;
        const int base = (hi << 6) | L;
#pragma unroll
        for (int m = 0; m < 8; ++m) x[m] = buf[fmap(base | (m << 3))];
        radix8(x, rtab[L << 7],
                  rtab[L << 6], rtab[(L << 6) + 512],
                  rtab[L << 5], rtab[(L << 5) + 256],
                  rtab[(L << 5) + 512], rtab[(L << 5) + 768]);
#pragma unroll
        for (int m = 0; m < 8; ++m) buf[fmap(base | (m << 3))] = x[m];
    }
    __syncthreads();

    // ---- phase 2: stages 7-9 (element stride 64) ----
    {
        const int L = tid & 63, hi = tid >> 6;
        const int base = (hi << 9) | L;
#pragma unroll
        for (int m = 0; m < 8; ++m) x[m] = buf[fmap(base | (m << 6))];
        radix8(x, rtab[L << 4],
                  rtab[L << 3], rtab[(L << 3) + 512],
                  rtab[L << 2], rtab[(L << 2) + 256],
                  rtab[(L << 2) + 512], rtab[(L << 2) + 768]);
#pragma unroll
        for (int m = 0; m < 8; ++m) buf[fmap(base | (m << 6))] = x[m];
    }
    __syncthreads();

    // ---- phase 3: stages 10-11 (radix-4, stride 512) + epilogue to global ----
    const uint32_t nm   = PASS2 ? to_mont(*ninv_p) : 0u;
    const uint32_t step = PASS2 ? 0u : to_mont(tw[col << 9]);   // Mont(w^(512*col))
#pragma unroll
    for (int g = 0; g < 2; ++g) {
        const int lo = tid + (g << 8);                           // < 512
        uint4 y[4];
#pragma unroll
        for (int m = 0; m < 4; ++m) y[m] = buf[fmap(lo | (m << 9))];
        const uint32_t t10  = rtab[lo << 1];
        const uint32_t t110 = rtab[lo];
        const uint32_t t111 = rtab[lo + 512];
        bf4(y[0], y[1], t10);  bf4(y[2], y[3], t10);
        bf4(y[0], y[2], t110); bf4(y[1], y[3], t111);

        if (!PASS2) {
            // middle twiddle Mont(w^(col*(lo + 512*m))), chained by step
            uint32_t tm = to_mont(tw[col * (uint32_t)lo]);       // exp < 2^21
#pragma unroll
            for (int m = 0; m < 4; ++m) {
                dst[col * (uint32_t)MSZ + (uint32_t)((m << 9) | lo)] = mm4(tm, y[m]);
                tm = mont_mul(tm, step);
            }
        } else {
#pragma unroll
            for (int m = 0; m < 4; ++m)
                dst[(uint32_t)((m << 9) | lo) * (uint32_t)MSZ + col] = mm4(nm, y[m]);
        }
    }
}

// ------------------------------- launch ------------------------------------
extern "C" void kernel_launch(void* const* d_in, const int* in_sizes, int n_in,
                              void* d_out, int out_size, void* d_ws, size_t ws_size,
                              hipStream_t stream)
{
    const uint4*    x    = (const uint4*)d_in[0];      // (N, 4) int32 rows
    const uint32_t* tw   = (const uint32_t*)d_in[1];   // w^k, k < 2^21
    const uint32_t* ninv = (const uint32_t*)d_in[2];
    uint4*          out  = (uint4*)d_out;

    intt_pass<false><<<dim3(2048), dim3(256), 0, stream>>>(x, out, tw, ninv);
    intt_pass<true ><<<dim3(2048), dim3(256), 0, stream>>>(out, out, tw, ninv);
}

// Round 3
// 209.619 us; speedup vs baseline: 1.1204x; 1.0327x over previous
//
#include <hip/hip_runtime.h>
#include <stdint.h>

// ---------------- modular arithmetic (Montgomery, R = 2^32) ----------------
static constexpr uint32_t P = 2013265921u;         // 15*2^27 + 1
static constexpr int      LOGM = 11;               // per-block DFT size 2048
static constexpr int      MSZ  = 1 << LOGM;
static constexpr int      NCOL = 4;                // batch columns per block

__host__ __device__ constexpr uint32_t neg_pinv32() {
    uint32_t x = 1u;
    for (int i = 0; i < 5; ++i) x *= 2u - P * x;
    return 0u - x;
}
static constexpr uint32_t NEG_PINV = neg_pinv32();
static constexpr uint32_t R1 = (uint32_t)(((uint64_t)1 << 32) % P);
static constexpr uint32_t R2 = (uint32_t)(((uint64_t)R1 * R1) % P);

__device__ __forceinline__ uint32_t mont_mul(uint32_t a, uint32_t b) {
    uint64_t t = (uint64_t)a * (uint64_t)b;
    uint32_t m = (uint32_t)t * NEG_PINV;
    uint32_t r = (uint32_t)((t + (uint64_t)m * P) >> 32);   // r < 2P
    uint32_t s = r - P;
    return s < r ? s : r;
}
__device__ __forceinline__ uint32_t to_mont(uint32_t a) { return mont_mul(a, R2); }
__device__ __forceinline__ uint32_t add_p(uint32_t a, uint32_t b) {
    uint32_t r = a + b, s = r - P; return s < r ? s : r;
}
__device__ __forceinline__ uint32_t sub_p(uint32_t a, uint32_t b) {
    uint32_t r = a - b, s = r + P; return s < r ? s : r;
}
__device__ __forceinline__ uint4 mm4(uint32_t w, uint4 v) {
    return make_uint4(mont_mul(w, v.x), mont_mul(w, v.y),
                      mont_mul(w, v.z), mont_mul(w, v.w));
}
__device__ __forceinline__ void bf4(uint4& L, uint4& H, uint32_t w) {
    uint4 t = mm4(w, H);
    uint4 l = L;
    L = make_uint4(add_p(l.x, t.x), add_p(l.y, t.y), add_p(l.z, t.z), add_p(l.w, t.w));
    H = make_uint4(sub_p(l.x, t.x), sub_p(l.y, t.y), sub_p(l.z, t.z), sub_p(l.w, t.w));
}

// Element swizzle (conflict-free for strides 1/8/64/512 per 8-lane phase
// groups: the two element-ids in each group differ in parity of g, so the
// 8 b128 accesses cover all 8 bank-quads). Flat uint4 index = g(el)*4 + c.
__device__ __forceinline__ int g_sw(int el) {
    return el ^ (((el >> 3) ^ (el >> 6)) & 7);
}
__device__ __forceinline__ int fidx(int el, int c) { return (g_sw(el) << 2) | c; }

// 3 DIT stages (radix-8) in registers.
__device__ __forceinline__ void radix8(uint4 x[8],
        uint32_t ta, uint32_t tb0, uint32_t tb1,
        uint32_t tc0, uint32_t tc1, uint32_t tc2, uint32_t tc3) {
    bf4(x[0], x[1], ta);  bf4(x[2], x[3], ta);
    bf4(x[4], x[5], ta);  bf4(x[6], x[7], ta);
    bf4(x[0], x[2], tb0); bf4(x[1], x[3], tb1);
    bf4(x[4], x[6], tb0); bf4(x[5], x[7], tb1);
    bf4(x[0], x[4], tc0); bf4(x[1], x[5], tc1);
    bf4(x[2], x[6], tc2); bf4(x[3], x[7], tc3);
}

// One 2048-pt inverse-DFT per workgroup over 4 adjacent batch columns.
// Thread t: column lane c4 = t&3 (global col c = 4*grp + c4), sub = t>>2
// owns 8 elements of its column. 4 consecutive lanes = 4 consecutive uint4
// = one full 64B line for every scattered global access.
// PASS1: read x[row*2048 + c] (bit-rev folded), write Y[c*2048+k2]*w^(c*k2).
// PASS2: read Y[i1*2048 + c], write out[k1*2048 + c]*n_inv (in-place safe:
//        per-column address set, disjoint across blocks).
template <bool PASS2>
__global__ __launch_bounds__(1024, 4) void intt_pass(
        const uint4* __restrict__ src, uint4* __restrict__ dst,
        const uint32_t* __restrict__ tw,
        const uint32_t* __restrict__ ninv_p)
{
    __shared__ uint4    buf[MSZ * NCOL];   // 128 KiB
    __shared__ uint32_t stab[2048];        // 8 KiB; stage s at [2^(s-1)-1 .. )

    const int      t   = threadIdx.x;
    const int      c4  = t & 3;
    const int      sub = t >> 2;           // [0,256)
    const uint32_t bid = blockIdx.x;
    const uint32_t grp = ((bid & 7u) << 6) | (bid >> 3);   // XCD swizzle, 512 grps
    const uint32_t c   = (grp << 2) | (uint32_t)c4;        // global column

    // per-stage twiddle table: stab[2^(s-1)-1 + j] = Mont(W^(j*2^(11-s))),
    // W = w^2048. Entry e: e+1 = 2^(s-1)+j  ->  tw[j << (21-(s-1))].
#pragma unroll
    for (int q = 0; q < 2; ++q) {
        int e = 2 * t + q;
        if (e < 2047) {
            uint32_t ep1 = (uint32_t)e + 1u;
            int sm1 = 31 - __clz((int)ep1);            // s-1
            uint32_t j = ep1 - (1u << sm1);
            stab[e] = to_mont(tw[j << (21 - sm1)]);
        }
    }

    // global gather, bit-reversal folded in: el = 8*sub+m <- row rev11(el)
    const uint32_t r8 = __brev((uint32_t)sub) >> 24;
    uint4 x[8];
#pragma unroll
    for (int m = 0; m < 8; ++m) {
        uint32_t r3 = __brev((uint32_t)m) >> 29;
        x[m] = src[((r3 << 8) | r8) * (uint32_t)MSZ + c];
    }
    __syncthreads();   // stab ready

    // ---- phase 0: stages 1-3 (j = 0) ----
    radix8(x, stab[0], stab[1], stab[2], stab[3], stab[4], stab[5], stab[6]);
#pragma unroll
    for (int m = 0; m < 8; ++m) buf[fidx(8 * sub + m, c4)] = x[m];
    __syncthreads();

    // ---- phase 1: stages 4-6 (element stride 8) ----
    {
        const int L = sub & 7, hi = sub >> 3;
        const int base = (hi << 6) | L;
#pragma unroll
        for (int m = 0; m < 8; ++m) x[m] = buf[fidx(base | (m << 3), c4)];
        radix8(x, stab[7 + L], stab[15 + L], stab[23 + L],
                  stab[31 + L], stab[39 + L], stab[47 + L], stab[55 + L]);
#pragma unroll
        for (int m = 0; m < 8; ++m) buf[fidx(base | (m << 3), c4)] = x[m];
    }
    __syncthreads();

    // ---- phase 2: stages 7-9 (element stride 64) ----
    {
        const int L = sub & 63, hi = sub >> 6;
        const int base = (hi << 9) | L;
#pragma unroll
        for (int m = 0; m < 8; ++m) x[m] = buf[fidx(base | (m << 6), c4)];
        radix8(x, stab[63 + L], stab[127 + L], stab[191 + L],
                  stab[255 + L], stab[319 + L], stab[383 + L], stab[447 + L]);
#pragma unroll
        for (int m = 0; m < 8; ++m) buf[fidx(base | (m << 6), c4)] = x[m];
    }
    __syncthreads();

    // ---- phase 3: stages 10-11 (stride 512) + epilogue ----
    uint32_t nm = 0u, s256 = 0u, step512 = 0u, tm0 = 0u;
    if (PASS2) {
        nm = to_mont(*ninv_p);
    } else {
        s256    = to_mont(tw[c << 8]);          // Mont(w^(256c))
        step512 = mont_mul(s256, s256);         // Mont(w^(512c))
        tm0     = to_mont(tw[c * (uint32_t)sub]);   // Mont(w^(c*sub)), exp < 2^19
    }
#pragma unroll
    for (int gg = 0; gg < 2; ++gg) {
        const int lo = sub + (gg << 8);          // [0,512)
        uint4 y[4];
#pragma unroll
        for (int m = 0; m < 4; ++m) y[m] = buf[fidx(lo | (m << 9), c4)];
        const uint32_t t10  = stab[511 + lo];
        const uint32_t t110 = stab[1023 + lo];
        const uint32_t t111 = stab[1535 + lo];
        bf4(y[0], y[1], t10);  bf4(y[2], y[3], t10);
        bf4(y[0], y[2], t110); bf4(y[1], y[3], t111);

        if (!PASS2) {
            uint32_t tm = tm0;                   // Mont(w^(c*lo))
#pragma unroll
            for (int m = 0; m < 4; ++m) {
                dst[c * (uint32_t)MSZ + (uint32_t)((m << 9) | lo)] = mm4(tm, y[m]);
                tm = mont_mul(tm, step512);
            }
            tm0 = mont_mul(tm0, s256);           // advance lo by 256 for gg=1
        } else {
#pragma unroll
            for (int m = 0; m < 4; ++m)
                dst[(uint32_t)((m << 9) | lo) * (uint32_t)MSZ + c] = mm4(nm, y[m]);
        }
    }
}

// ------------------------------- launch ------------------------------------
extern "C" void kernel_launch(void* const* d_in, const int* in_sizes, int n_in,
                              void* d_out, int out_size, void* d_ws, size_t ws_size,
                              hipStream_t stream)
{
    const uint4*    x    = (const uint4*)d_in[0];      // (N, 4) int32 rows
    const uint32_t* tw   = (const uint32_t*)d_in[1];   // w^k, k < 2^21
    const uint32_t* ninv = (const uint32_t*)d_in[2];
    uint4*          out  = (uint4*)d_out;

    intt_pass<false><<<dim3(512), dim3(1024), 0, stream>>>(x, out, tw, ninv);
    intt_pass<true ><<<dim3(512), dim3(1024), 0, stream>>>(out, out, tw, ninv);
}